// Round 1
// baseline (273.917 us; speedup 1.0000x reference)
//
#include <hip/hip_runtime.h>

// Problem constants (fixed by reference setup_inputs)
#define B_    8
#define C_    16
#define T_    2000
#define F_    128
#define POOL_ 10
#define T1_   200          // T_/POOL_ (exact, no tail)
#define BC_   (B_*C_)      // 128
#define EPS_  1e-5f

// ---------------------------------------------------------------------------
// K1: per-(bc,t1) block sums of x and x^2 over the 10-step pooled window.
// grid = BC_ * (T1_/8) = 3200 blocks, 256 threads.
// Each 32-thread group (f4 = tid&31) covers one t1's 128 features as float4.
// ---------------------------------------------------------------------------
__global__ __launch_bounds__(256) void k1_blocksums(
    const float4* __restrict__ x4, float4* __restrict__ S4, float4* __restrict__ S24)
{
    int bid = blockIdx.x;
    int bc  = bid / (T1_ / 8);
    int t1  = (bid % (T1_ / 8)) * 8 + (threadIdx.x >> 5);
    int f4  = threadIdx.x & 31;

    const float4* p = x4 + (size_t)(bc * T_ + t1 * POOL_) * (F_ / 4) + f4;
    float4 s  = {0.f, 0.f, 0.f, 0.f};
    float4 s2 = {0.f, 0.f, 0.f, 0.f};
#pragma unroll
    for (int k = 0; k < POOL_; ++k) {
        float4 v = p[(size_t)k * (F_ / 4)];
        s.x += v.x; s.y += v.y; s.z += v.z; s.w += v.w;
        s2.x = fmaf(v.x, v.x, s2.x);
        s2.y = fmaf(v.y, v.y, s2.y);
        s2.z = fmaf(v.z, v.z, s2.z);
        s2.w = fmaf(v.w, v.w, s2.w);
    }
    size_t o = (size_t)(bc * T1_ + t1) * (F_ / 4) + f4;
    S4[o]  = s;
    S24[o] = s2;
}

// ---------------------------------------------------------------------------
// K2: in-place causal scan over t1 per (bc,f).
// S -> prefix mean, S2 -> prefix rstd.  One thread per (bc,f) column.
// grid = BC_*F_/64 = 512 blocks, 64 threads; consecutive threads = consecutive
// f -> coalesced stride-F_ column walk.
// ---------------------------------------------------------------------------
__global__ __launch_bounds__(64) void k2_scan(
    float* __restrict__ S, float* __restrict__ S2)
{
    int g  = blockIdx.x * 64 + threadIdx.x;   // g = bc*F_ + f
    int bc = g / F_;
    int f  = g - bc * F_;

    float rs = 0.f, rs2 = 0.f;
    size_t idx = (size_t)bc * T1_ * F_ + f;
#pragma unroll 4
    for (int t1 = 0; t1 < T1_; ++t1, idx += F_) {
        rs  += S[idx];
        rs2 += S2[idx];
        float inv = 1.0f / (float)((t1 + 1) * POOL_);
        float m   = rs  * inv;
        float m2  = rs2 * inv;
        float var = m2 - m * m;
        S[idx]  = m;
        S2[idx] = rsqrtf(var + EPS_);
    }
}

// ---------------------------------------------------------------------------
// K3: normalize. out = (x - mean[t/10]) * rstd[t/10].  Fully parallel float4.
// grid = BC_*T_*F_/4/256 = 32000 blocks, 256 threads.
// ---------------------------------------------------------------------------
__global__ __launch_bounds__(256) void k3_norm(
    const float4* __restrict__ x4, const float4* __restrict__ M4,
    const float4* __restrict__ R4, float4* __restrict__ out4)
{
    int gid = blockIdx.x * 256 + threadIdx.x;   // float4 index
    int f4  = gid & (F_ / 4 - 1);               // gid & 31
    int tmp = gid >> 5;                         // bc*T_ + t
    int t   = tmp % T_;
    int bc  = tmp / T_;

    size_t sidx = (size_t)(bc * T1_ + t / POOL_) * (F_ / 4) + f4;
    float4 xv = x4[gid];
    float4 m  = M4[sidx];
    float4 r  = R4[sidx];
    float4 o;
    o.x = (xv.x - m.x) * r.x;
    o.y = (xv.y - m.y) * r.y;
    o.z = (xv.z - m.z) * r.z;
    o.w = (xv.w - m.w) * r.w;
    out4[gid] = o;
}

extern "C" void kernel_launch(void* const* d_in, const int* in_sizes, int n_in,
                              void* d_out, int out_size, void* d_ws, size_t ws_size,
                              hipStream_t stream)
{
    const float* x   = (const float*)d_in[0];
    float*       out = (float*)d_out;

    // Workspace: S (13.1 MB) + S2 (13.1 MB) = 26.2 MB. Fully written by K1
    // before K2 reads, so 0xAA poison is harmless.
    float* S  = (float*)d_ws;
    float* S2 = S + (size_t)BC_ * T1_ * F_;

    k1_blocksums<<<BC_ * (T1_ / 8), 256, 0, stream>>>(
        (const float4*)x, (float4*)S, (float4*)S2);

    k2_scan<<<BC_ * F_ / 64, 64, 0, stream>>>(S, S2);

    k3_norm<<<(BC_ * T_ * (F_ / 4)) / 256, 256, 0, stream>>>(
        (const float4*)x, (const float4*)S, (const float4*)S2, (float4*)out);
}